// Round 3
// baseline (543.960 us; speedup 1.0000x reference)
//
#include <hip/hip_runtime.h>
#include <stdint.h>

typedef unsigned short u16;
typedef unsigned int u32;

// ---------------- constants ----------------
#define BATCH 2
#define NSEQ  4096
#define DIM   1024
#define HEADS 16
#define DH    64
#define WIN   512
#define INNER 2730
#define ROWS  8192
#define QKV_N 3072
#define FF1_N 5460
#define FF1_NP 5632      // padded N for ff1 (22*256)
#define INNER_P 2816     // padded K for ff2 (88*32)
#define KROT 0.28782313663f   // ln(10000)/32

typedef __attribute__((ext_vector_type(8))) short short8;
typedef __attribute__((ext_vector_type(4))) float float4v;

__device__ __forceinline__ float bf2f(u16 u){ union{u32 i;float f;}c; c.i=((u32)u)<<16; return c.f; }
__device__ __forceinline__ u16 f2bf(float f){ union{float f;u32 i;}c; c.f=f; u32 i=c.i;
    return (u16)((i + 0x7FFFu + ((i>>16)&1u))>>16); }

// fast GELU (tanh form via hw exp): |err vs exact| <= ~3e-3, fine at 0.109 threshold
__device__ __forceinline__ float gelu_fast(float g) {
    float t = 0.7978845608f * (g + 0.044715f * g * g * g);
    float th = 1.f - 2.f / (1.f + __expf(2.f * t));
    return 0.5f * g * (1.f + th);
}

// async global->LDS, 16B per lane. LDS dest = wave-uniform base + lane*16; global src may scatter per lane.
__device__ __forceinline__ void gl_lds16(const u16* g, const u16* ldsbase) {
    __builtin_amdgcn_global_load_lds(
        (const __attribute__((address_space(1))) u32*)(uintptr_t)g,
        (__attribute__((address_space(3))) u32*)(uintptr_t)ldsbase,
        16, 0, 0);
}

// ff1 interleave mapping: output row n' of wf1t -> source column of w_ff1
__device__ __forceinline__ int ff1_src(int n, bool& ok) {
    int t = n >> 7, m = n & 127, j = m >> 4, l = m & 15;
    int p = t * 64 + ((j >> 1) << 4) + l;
    ok = (p < INNER);
    return (j & 1) ? (INNER + p) : p;
}

// ---------------- weight transpose + cast: wt[n][k] = bf16(w[k][src(n)]), zero-padded ----------------
template <bool REMAP>
__global__ __launch_bounds__(256) void wtrans_kernel(const float* __restrict__ w, u16* __restrict__ wt,
                                                     int K0, int N0, int K1, int N1) {
    __shared__ float tile[32][33];
    int kt = blockIdx.x, nt = blockIdx.y;
    int tx = threadIdx.x & 31, ty = threadIdx.x >> 5;
    int nl = nt * 32 + tx;
    bool ok = (nl < N1);
    int sc = nl;
    if (REMAP) { bool v; sc = ff1_src(nl < N1 ? nl : 0, v); ok = ok && v; }
    else ok = ok && (nl < N0);
#pragma unroll
    for (int yy = 0; yy < 4; yy++) {
        int k = kt*32 + ty + yy*8;
        tile[ty+yy*8][tx] = (k < K0 && ok) ? w[(size_t)k*N0 + sc] : 0.f;
    }
    __syncthreads();
#pragma unroll
    for (int yy = 0; yy < 4; yy++) {
        int n = nt*32 + ty + yy*8, k = kt*32 + tx;
        if (n < N1 && k < K1) wt[(size_t)n*K1 + k] = f2bf(tile[tx][ty+yy*8]);
    }
}

// ---------------- LayerNorm: fp32 in, bf16 out (dim = 1024) ----------------
__global__ __launch_bounds__(256) void ln_kernel(const float* __restrict__ x,
                                                 const float* __restrict__ w,
                                                 const float* __restrict__ b,
                                                 u16* __restrict__ out) {
    int row = blockIdx.x;
    const float* xr = x + (size_t)row * DIM;
    int t = threadIdx.x;
    float v[4];
    float s = 0.f, s2 = 0.f;
#pragma unroll
    for (int i = 0; i < 4; i++) {
        float f = xr[t + 256 * i];
        v[i] = f; s += f; s2 += f * f;
    }
#pragma unroll
    for (int off = 32; off; off >>= 1) { s += __shfl_xor(s, off); s2 += __shfl_xor(s2, off); }
    __shared__ float ls[10];
    int wave = t >> 6, lane = t & 63;
    if (lane == 0) { ls[wave] = s; ls[4 + wave] = s2; }
    __syncthreads();
    if (t == 0) {
        float ts  = ls[0] + ls[1] + ls[2] + ls[3];
        float ts2 = ls[4] + ls[5] + ls[6] + ls[7];
        float mean = ts * (1.f / DIM);
        float var  = ts2 * (1.f / DIM) - mean * mean;
        ls[8] = mean; ls[9] = 1.f / sqrtf(var + 1e-5f);
    }
    __syncthreads();
    float mean = ls[8], inv = ls[9];
    u16* orow = out + (size_t)row * DIM;
#pragma unroll
    for (int i = 0; i < 4; i++) {
        int c = t + 256 * i;
        float y = (v[i] - mean) * inv * w[c];
        if (b) y += b[c];
        orow[c] = f2bf(y);
    }
}

// ---------------- 256x256 GEMM, BK=32, 4-deep ring, 2-phase/K-step interleave ----------------
// MODE 2: bf16 out + rotary/scale (qkv).  MODE 3: bf16 GEGLU out (ff1, interleaved wf1t).
// 8 waves (2M x 4N), per-wave 128x64 output (8x4 frags). LDS: 4 ring buffers x (A 256x32 + B 256x32).
// Each K-step split into 2 phases of 16 MFMA (m201-style interleave):
//   phase0: ds_read af[0..3]+bfr[0..3], stage A-half of tile t+3, bar, lgkm0, 16 MFMA, bar
//   phase1: ds_read af[4..7],           stage B-half of tile t+3, bar, lgkm0, 16 MFMA
//   end:    s_waitcnt vmcnt(8/4/0) [tile t+1 resident], bar
// WAR-safe: buf[(t+3)&3]=buf[(t-1)&3]; tile t-1's last reader drained at its lgkm0 before
// step t-1's final barrier. Counted vmcnt never 0 in steady state.
template <int MODE>
__global__ __launch_bounds__(512, 2) void gemm256(const u16* __restrict__ A,
                                                  const u16* __restrict__ Bt,
                                                  void* __restrict__ Cv,
                                                  int N, int K) {
    extern __shared__ u16 lds[];
    u16* Asm = lds;             // [4][256*32]
    u16* Bsm = lds + 4 * 8192;  // [4][256*32]
    int tiles_n = N >> 8;
    int gs  = tiles_n << 3;
    int gid = blockIdx.x / gs;
    int loc = blockIdx.x % gs;
    int tm = gid * 8 + (loc & 7);
    int tn = loc >> 3;
    int tid = threadIdx.x, wave = tid >> 6, lane = tid & 63;
    int quad = lane >> 4, l15 = lane & 15;
    int wm = wave >> 2, wn = wave & 3;
    int srow = wave * 16 + (lane >> 2);                 // staging row within 128-row half
    int sgrp = (lane & 3) ^ ((srow >> 1) & 3);          // swizzled source 16B group
    const u16* Ag = A  + (size_t)(tm * 256 + srow) * K + sgrp * 8;
    const u16* Bg = Bt + (size_t)(tn * 256 + srow) * K + sgrp * 8;
    u16* Asw = Asm + wave * 512;                        // wave's linear LDS dest (1024B)
    u16* Bsw = Bsm + wave * 512;
    int rg = (l15 >> 1) & 3;                            // reader swizzle term
    int nk = K >> 5;

    float4v acc[8][4];
#pragma unroll
    for (int i = 0; i < 8; i++)
#pragma unroll
        for (int j = 0; j < 4; j++) acc[i][j] = (float4v){0.f, 0.f, 0.f, 0.f};

    auto stage2 = [&](int t, int h) {
        int b = t & 3;
        int k0 = t << 5;
        if (h == 0) {
            gl_lds16(Ag + k0,                   Asw + b * 8192);
            gl_lds16(Ag + (size_t)128 * K + k0, Asw + b * 8192 + 4096);
        } else {
            gl_lds16(Bg + k0,                   Bsw + b * 8192);
            gl_lds16(Bg + (size_t)128 * K + k0, Bsw + b * 8192 + 4096);
        }
    };
    auto ldsA = [&](int t, int i) -> short8 {
        const u16* Ab = Asm + (t & 3) * 8192;
        return *(const short8*)&Ab[(wm*128 + i*16 + l15) * 32 + ((quad ^ rg) * 8)];
    };
    auto ldsB = [&](int t, int j) -> short8 {
        const u16* Bb = Bsm + (t & 3) * 8192;
        return *(const short8*)&Bb[(wn*64 + j*16 + l15) * 32 + ((quad ^ rg) * 8)];
    };

    // prologue: 3 tiles in flight (12 loads), wait for tile 0 (8 newest = tiles 1,2 remain)
    stage2(0, 0); stage2(0, 1);
    stage2(1, 0); stage2(1, 1);
    stage2(2, 0); stage2(2, 1);
    asm volatile("s_waitcnt vmcnt(8)" ::: "memory");
    __builtin_amdgcn_s_barrier();

    for (int t = 0; t < nk; ++t) {
        short8 af[8], bfr[4];
        // ---- phase 0 ----
#pragma unroll
        for (int i = 0; i < 4; i++) af[i] = ldsA(t, i);
#pragma unroll
        for (int j = 0; j < 4; j++) bfr[j] = ldsB(t, j);
        if (t + 3 < nk) stage2(t + 3, 0);
        __builtin_amdgcn_s_barrier();
        asm volatile("s_waitcnt lgkmcnt(0)" ::: "memory");
        __builtin_amdgcn_sched_barrier(0);
        __builtin_amdgcn_s_setprio(1);
#pragma unroll
        for (int i = 0; i < 4; i++)
#pragma unroll
            for (int j = 0; j < 4; j++)
                acc[i][j] = __builtin_amdgcn_mfma_f32_16x16x32_bf16(af[i], bfr[j], acc[i][j], 0, 0, 0);
        __builtin_amdgcn_s_setprio(0);
        __builtin_amdgcn_s_barrier();
        // ---- phase 1 ----
#pragma unroll
        for (int i = 4; i < 8; i++) af[i] = ldsA(t, i);
        if (t + 3 < nk) stage2(t + 3, 1);
        __builtin_amdgcn_s_barrier();
        asm volatile("s_waitcnt lgkmcnt(0)" ::: "memory");
        __builtin_amdgcn_sched_barrier(0);
        __builtin_amdgcn_s_setprio(1);
#pragma unroll
        for (int i = 4; i < 8; i++)
#pragma unroll
            for (int j = 0; j < 4; j++)
                acc[i][j] = __builtin_amdgcn_mfma_f32_16x16x32_bf16(af[i], bfr[j], acc[i][j], 0, 0, 0);
        __builtin_amdgcn_s_setprio(0);
        // ---- end of K-step: ensure tile t+1 resident before next step's reads ----
        if (t < nk - 1) {
            if (t < nk - 3)       asm volatile("s_waitcnt vmcnt(8)" ::: "memory");
            else if (t == nk - 3) asm volatile("s_waitcnt vmcnt(4)" ::: "memory");
            else                  asm volatile("s_waitcnt vmcnt(0)" ::: "memory");
            __builtin_amdgcn_s_barrier();
        }
    }

    // ---------------- epilogues ----------------
    if (MODE == 2) {
        u16* C = (u16*)Cv;
        int sector = tn >> 2;                       // 0=q,1=k,2=v (256-col tiles, 4 per 1024)
        if (sector < 2) {
            float inv0 = __expf(-(float)l15 * KROT);
            float inv1 = __expf(-(float)(l15 + 16) * KROT);
            float sc = (sector == 0) ? 0.125f : 1.0f;
#pragma unroll
            for (int i = 0; i < 8; i++) {
#pragma unroll
                for (int r = 0; r < 4; r++) {
                    int row = tm*256 + wm*128 + i*16 + quad*4 + r;
                    float fn = (float)(row & (NSEQ - 1));
                    float s0, c0, s1, c1;
                    __sincosf(fn * inv0, &s0, &c0);
                    __sincosf(fn * inv1, &s1, &c1);
                    float a0 = acc[i][0][r], a1 = acc[i][1][r];
                    float a2 = acc[i][2][r], a3 = acc[i][3][r];
                    size_t base = (size_t)row * N + tn*256 + wn*64 + l15;
                    C[base]      = f2bf((a0*c0 - a2*s0) * sc);
                    C[base + 16] = f2bf((a1*c1 - a3*s1) * sc);
                    C[base + 32] = f2bf((a2*c0 + a0*s0) * sc);
                    C[base + 48] = f2bf((a3*c1 + a1*s1) * sc);
                }
            }
        } else {
#pragma unroll
            for (int i = 0; i < 8; i++)
#pragma unroll
                for (int r = 0; r < 4; r++) {
                    size_t base = (size_t)(tm*256 + wm*128 + i*16 + quad*4 + r) * N + tn*256 + wn*64 + l15;
#pragma unroll
                    for (int j = 0; j < 4; j++) C[base + j*16] = f2bf(acc[i][j][r]);
                }
        }
        return;
    }
    if (MODE == 3) {
        u16* ag = (u16*)Cv;
        int t128 = tn * 2 + (wn >> 1);              // 128-col block index in C
        int cb = t128 * 64 + (wn & 1) * 32;         // output col base in ag
#pragma unroll
        for (int i = 0; i < 8; i++) {
#pragma unroll
            for (int r = 0; r < 4; r++) {
                size_t row = (size_t)(tm*256 + wm*128 + i*16 + quad*4 + r);
#pragma unroll
                for (int jp = 0; jp < 2; jp++) {
                    float a = acc[i][2*jp][r];
                    float g = acc[i][2*jp+1][r];
                    int col = cb + jp*16 + l15;
                    ag[row * INNER_P + col] = f2bf(a * gelu_fast(g));
                }
            }
        }
        return;
    }
}

// ---------------- GEMM: C[M,N] = A[M,K] @ Bt[N,K]^T, fused epilogues (128^2, 2-phase) ----------------
// MODE 1: fp32 out + fp32 resid (w_out, ff2). Kept known-good for the N=1024 GEMMs.
template <int MODE>
__global__ __launch_bounds__(256) void gemm_tile(const u16* __restrict__ A,
                                                 const u16* __restrict__ Bt,
                                                 const float* __restrict__ resid,
                                                 void* __restrict__ Cv,
                                                 int M, int N, int K) {
    __shared__ u16 As[2][128 * 32];
    __shared__ u16 Bs[2][128 * 32];
    int tiles_n = N >> 7;
    int gs  = tiles_n << 3;
    int gid = blockIdx.x / gs;
    int loc = blockIdx.x % gs;
    int tm = gid * 8 + (loc & 7);
    int tn = loc >> 3;
    int tid = threadIdx.x, wave = tid >> 6, lane = tid & 63;
    int quad = lane >> 4, l15 = lane & 15;
    int wm = wave >> 1, wn = wave & 1;
    int srow = wave * 32 + (lane >> 2);
    int sgrp = (lane & 3) ^ ((srow >> 1) & 3);
    const u16* Ag = A  + (size_t)(tm * 128 + srow) * K + sgrp * 8;
    const u16* Bg = Bt + (size_t)(tn * 128 + srow) * K + sgrp * 8;
    const u16* Alb0 = &As[0][wave * 1024];
    const u16* Blb0 = &Bs[0][wave * 1024];
    const u16* Alb1 = &As[1][wave * 1024];
    const u16* Blb1 = &Bs[1][wave * 1024];
    int rg = (l15 >> 1) & 3;
    float4v acc[4][4];
#pragma unroll
    for (int i = 0; i < 4; i++)
#pragma unroll
        for (int j = 0; j < 4; j++) acc[i][j] = (float4v){0.f, 0.f, 0.f, 0.f};

    gl_lds16(Ag,                Alb0);
    gl_lds16(Ag + (size_t)16*K, Alb0 + 512);
    gl_lds16(Bg,                Blb0);
    gl_lds16(Bg + (size_t)16*K, Blb0 + 512);
    __syncthreads();

    int nk = K >> 5;
    for (int t = 0; t < nk; ++t) {
        int buf = t & 1;
        if (t + 1 < nk) {
            int k0 = (t + 1) << 5;
            const u16* Al = buf ? Alb0 : Alb1;
            const u16* Bl = buf ? Blb0 : Blb1;
            gl_lds16(Ag + k0,                Al);
            gl_lds16(Ag + (size_t)16*K + k0, Al + 512);
            gl_lds16(Bg + k0,                Bl);
            gl_lds16(Bg + (size_t)16*K + k0, Bl + 512);
        }
        const u16* Asb = &As[buf][0];
        const u16* Bsb = &Bs[buf][0];
        short8 af[4], bf[4];
#pragma unroll
        for (int i = 0; i < 4; i++)
            af[i] = *(const short8*)&Asb[(wm*64 + i*16 + l15)*32 + ((quad ^ rg) * 8)];
#pragma unroll
        for (int j = 0; j < 4; j++)
            bf[j] = *(const short8*)&Bsb[(wn*64 + j*16 + l15)*32 + ((quad ^ rg) * 8)];
#pragma unroll
        for (int i = 0; i < 4; i++)
#pragma unroll
            for (int j = 0; j < 4; j++)
                acc[i][j] = __builtin_amdgcn_mfma_f32_16x16x32_bf16(af[i], bf[j], acc[i][j], 0, 0, 0);
        __syncthreads();
    }
#pragma unroll
    for (int i = 0; i < 4; i++) {
#pragma unroll
        for (int r = 0; r < 4; r++) {
            size_t row = (size_t)(tm*128 + wm*64 + i*16 + quad*4 + r);
#pragma unroll
            for (int j = 0; j < 4; j++) {
                int col = tn*128 + wn*64 + j*16 + l15;
                size_t idx = row * N + col;
                float v = acc[i][j][r];
                if (MODE == 1) { if (resid) v += resid[idx]; ((float*)Cv)[idx] = v; }
                else ((u16*)Cv)[idx] = f2bf(v);
            }
        }
    }
}

// ---------------- V transpose: vt[b][h][d][n] = qkv.v[b,n,h,d] ----------------
__global__ __launch_bounds__(256) void vtrans_kernel(const u16* __restrict__ qkv, u16* __restrict__ vt) {
    __shared__ u16 tile[64][72];
    int t = threadIdx.x;
    int n0 = (blockIdx.x & 63) * 64;
    int hh = (blockIdx.x >> 6) & 15;
    int b  = blockIdx.x >> 10;
    int r = t >> 2, cb = (t & 3) * 16;
    const u16* src = qkv + (size_t)(b * NSEQ + n0 + r) * QKV_N + 2 * DIM + hh * 64 + cb;
    uint4 v0 = *(const uint4*)(src);
    uint4 v1 = *(const uint4*)(src + 8);
    *(uint4*)&tile[r][cb]     = v0;
    *(uint4*)&tile[r][cb + 8] = v1;
    __syncthreads();
    int d = t >> 2, nb = (t & 3) * 16;
    __align__(16) u16 vals[16];
#pragma unroll
    for (int e = 0; e < 16; e++) vals[e] = tile[nb + e][d];
    u16* dst = vt + ((size_t)(b * HEADS + hh) * DH + d) * NSEQ + n0 + nb;
    *(uint4*)(dst)     = *(uint4*)&vals[0];
    *(uint4*)(dst + 8) = *(uint4*)&vals[8];
}

// ---------------- MFMA flash attention, block-cooperative LDS staging ----------------
__global__ __launch_bounds__(256) void attn_kernel(const u16* __restrict__ qkv,
                                                   const u16* __restrict__ vt,
                                                   u16* __restrict__ o) {
    __shared__ u16 Ks[128 * 64];
    __shared__ u16 Vs[64 * 128];
    __shared__ u16 p_lds[4][16][136];
    int tid = threadIdx.x, wave = tid >> 6, lane = tid & 63;
    int quad = lane >> 4, l15 = lane & 15;
    int bi = blockIdx.x;
    int qb = bi & 7, w0 = (bi >> 3) & 7, hh = (bi >> 6) & 15, b = bi >> 10;
    int qt = qb * 4 + wave;
    int qlocal = qt * 16 + l15;
    const u16* qp = qkv + (size_t)(b*NSEQ + w0*WIN + qt*16 + l15) * QKV_N + hh*64 + quad*8;
    short8 bq0 = *(const short8*)(qp);
    short8 bq1 = *(const short8*)(qp + 32);
    int krow0 = b * NSEQ + (w0 - 1) * WIN;
    const u16* vbase = vt + (size_t)(b * HEADS + hh) * DH * NSEQ + (w0 - 1) * WIN;
    int ks_row = lane >> 3;
    int ks_g   = (lane & 7) ^ ks_row;
    int vs_row = lane >> 4;
    int vs_j0  = lane & 15;
    int swz = l15 & 7;
    float m_ = -1e30f, l_ = 0.f;
    float4v O[4] = {{0,0,0,0},{0,0,0,0},{0,0,0,0},{0,0,0,0}};
    int cstart = (w0 == 0) ? 4 : 0;
    int clast  = (512 + qb * 64 + 63) >> 7;
    u16 (*pt)[136] = p_lds[wave];
    for (int c = cstart; c <= clast; c++) {
        int kb = c * 128;
        __syncthreads();
#pragma unroll
        for (int i = 0; i < 4; i++) {
            int kloc = wave * 32 + i * 8 + ks_row;
            gl_lds16(qkv + (size_t)(krow0 + kb + kloc) * QKV_N + DIM + hh*64 + ks_g*8,
                     &Ks[(wave*32 + i*8) * 64]);
        }
#pragma unroll
        for (int i = 0; i < 4; i++) {
            int dloc = wave * 16 + i * 4 + vs_row;
            int jsrc = vs_j0 ^ (dloc & 7);
            gl_lds16(vbase + (size_t)dloc * NSEQ + kb + jsrc * 8,
                     &Vs[(wave*16 + i*4) * 128]);
        }
        __syncthreads();
        float4v s[8];
#pragma unroll
        for (int t = 0; t < 8; t++) {
            int krow = (t*16 + l15) * 64;
            short8 ka0 = *(const short8*)&Ks[krow + ((quad    ) ^ swz) * 8];
            short8 ka1 = *(const short8*)&Ks[krow + ((quad + 4) ^ swz) * 8];
            float4v st = {0.f, 0.f, 0.f, 0.f};
            st = __builtin_amdgcn_mfma_f32_16x16x32_bf16(ka0, bq0, st, 0, 0, 0);
            st = __builtin_amdgcn_mfma_f32_16x16x32_bf16(ka1, bq1, st, 0, 0, 0);
            int ck = kb + t*16 + quad*4;
#pragma unroll
            for (int r = 0; r < 4; r++)
                if (ck + r >= 512 && ck + r - 512 > qlocal) st[r] = -1e30f;
            s[t] = st;
        }
        float mc = -1e30f;
#pragma unroll
        for (int t = 0; t < 8; t++)
#pragma unroll
            for (int r = 0; r < 4; r++) mc = fmaxf(mc, s[t][r]);
        mc = fmaxf(mc, __shfl_xor(mc, 16));
        mc = fmaxf(mc, __shfl_xor(mc, 32));
        float mn = fmaxf(m_, mc);
        float alpha = __expf(m_ - mn);
        m_ = mn;
        float su = 0.f;
#pragma unroll
        for (int t = 0; t < 8; t++) {
            union { u16 h[4]; uint2 v; } pk;
#pragma unroll
            for (int r = 0; r < 4; r++) {
                float p = __expf(s[t][r] - mn);
                su += p;
                pk.h[r] = f2bf(p);
            }
            *(uint2*)&pt[l15][t*16 + quad*4] = pk.v;
        }
        su += __shfl_xor(su, 16);
        su += __shfl_xor(su, 32);
        l_ = l_ * alpha + su;
#pragma unroll
        for (int t = 0; t < 4; t++)
#pragma unroll
            for (int r = 0; r < 4; r++) O[t][r] *= alpha;
#pragma unroll
        for (int g = 0; g < 4; g++) {
            short8 pf = *(const short8*)&pt[l15][g*32 + quad*8];
#pragma unroll
            for (int t = 0; t < 4; t++) {
                short8 vf = *(const short8*)&Vs[(t*16 + l15) * 128 + ((g*4 + quad) ^ swz) * 8];
                O[t] = __builtin_amdgcn_mfma_f32_16x16x32_bf16(vf, pf, O[t], 0, 0, 0);
            }
        }
    }
    float inv = 1.f / l_;
    u16* op = o + (size_t)(b*NSEQ + w0*WIN + qt*16 + l15) * DIM + hh*64;
#pragma unroll
    for (int t = 0; t < 4; t++) {
        union { u16 h[4]; uint2 v; } pk;
#pragma unroll
        for (int r = 0; r < 4; r++) pk.h[r] = f2bf(O[t][r] * inv);
        *(uint2*)(op + t*16 + quad*4) = pk.v;
    }
}

// ---------------- launch ----------------
extern "C" void kernel_launch(void* const* d_in, const int* in_sizes, int n_in,
                              void* d_out, int out_size, void* d_ws, size_t ws_size,
                              hipStream_t stream) {
    const float* x      = (const float*)d_in[0];
    const float* ln1_w  = (const float*)d_in[1];
    const float* ln1_b  = (const float*)d_in[2];
    const float* w_qkv  = (const float*)d_in[3];
    const float* w_out  = (const float*)d_in[4];
    const float* ln2_w  = (const float*)d_in[5];
    const float* w_ff1  = (const float*)d_in[6];
    const float* w_ff2  = (const float*)d_in[7];
    float* out = (float*)d_out;

    static bool cfg = false;
    if (!cfg) {
        hipFuncSetAttribute((const void*)gemm256<2>, hipFuncAttributeMaxDynamicSharedMemorySize, 131072);
        hipFuncSetAttribute((const void*)gemm256<3>, hipFuncAttributeMaxDynamicSharedMemorySize, 131072);
        cfg = true;
    }

    char* ws = (char*)d_ws;
    size_t off = 0;
    auto alloc = [&](size_t bytes) { size_t o = off; off += (bytes + 255) & ~(size_t)255; return o; };
    size_t off_wqt  = alloc((size_t)QKV_N  * DIM * 2);
    size_t off_wot  = alloc((size_t)DIM    * DIM * 2);
    size_t off_wf1t = alloc((size_t)FF1_NP * DIM * 2);
    size_t off_wf2t = alloc((size_t)DIM    * INNER_P * 2);
    size_t off_h    = alloc((size_t)ROWS * DIM * 2);
    size_t sz_qkv = (size_t)ROWS * QKV_N * 2;
    size_t sz_vt  = (size_t)BATCH * HEADS * DH * NSEQ * 2;
    size_t off_qkv  = alloc(sz_qkv);
    size_t off_vt   = alloc(sz_vt);
    size_t off_o    = alloc((size_t)ROWS * DIM * 2);
    size_t off_x1   = alloc((size_t)ROWS * DIM * 4);
    size_t off_ag   = alloc((size_t)ROWS * INNER_P * 2);

    u16* wqt  = (u16*)(ws + off_wqt);
    u16* wot  = (u16*)(ws + off_wot);
    u16* wf1t = (u16*)(ws + off_wf1t);
    u16* wf2t = (u16*)(ws + off_wf2t);
    u16* h    = (u16*)(ws + off_h);
    u16* qkv  = (u16*)(ws + off_qkv);
    u16* vt   = (u16*)(ws + off_vt);
    u16* o    = (u16*)(ws + off_o);
    float* x1 = (float*)(ws + off_x1);
    u16* ag   = (u16*)(ws + off_ag);

    // 0) transpose+cast weights -> bf16 [N][K]; ff1 column-interleaved (a,g) pairs
    wtrans_kernel<false><<<dim3(32, 96),  256, 0, stream>>>(w_qkv, wqt,  DIM,   QKV_N, DIM,     QKV_N);
    wtrans_kernel<false><<<dim3(32, 32),  256, 0, stream>>>(w_out, wot,  DIM,   DIM,   DIM,     DIM);
    wtrans_kernel<true ><<<dim3(32, 176), 256, 0, stream>>>(w_ff1, wf1t, DIM,   FF1_N, DIM,     FF1_NP);
    wtrans_kernel<false><<<dim3(88, 32),  256, 0, stream>>>(w_ff2, wf2t, INNER, DIM,   INNER_P, DIM);

    // 1) LN1
    ln_kernel<<<ROWS, 256, 0, stream>>>(x, ln1_w, ln1_b, h);
    // 2) qkv = h @ w_qkv, rotary+scale fused in epilogue (256^2 ring kernel)
    gemm256<2><<<(ROWS/256) * (QKV_N/256), 512, 131072, stream>>>(h, wqt, qkv, QKV_N, DIM);
    // 3) V transpose
    vtrans_kernel<<<BATCH * HEADS * (NSEQ / 64), 256, 0, stream>>>(qkv, vt);
    // 4) attention
    attn_kernel<<<BATCH * HEADS * 8 * 8, 256, 0, stream>>>(qkv, vt, o);
    // 5) x1 = o @ w_out + x
    gemm_tile<1><<<(ROWS/128) * (DIM/128), 256, 0, stream>>>(o, wot, x, x1, ROWS, DIM, DIM);
    // 6) h2 = LN2(x1)
    ln_kernel<<<ROWS, 256, 0, stream>>>(x1, ln2_w, nullptr, h);
    // 7) ag = geglu(h2 @ w_ff1) fused (interleaved wf1t), writes [8192 x 2816] (256^2 ring kernel)
    gemm256<3><<<(ROWS/256) * (FF1_NP/256), 512, 131072, stream>>>(h, wf1t, ag, FF1_NP, DIM);
    // 8) out = ag @ w_ff2 + x1
    gemm_tile<1><<<(ROWS/128) * (DIM/128), 256, 0, stream>>>(ag, wf2t, x1, out, ROWS, DIM, INNER_P);

    (void)in_sizes; (void)n_in; (void)out_size; (void)ws_size;
}

// Round 4
// 527.371 us; speedup vs baseline: 1.0315x; 1.0315x over previous
//
#include <hip/hip_runtime.h>
#include <stdint.h>

typedef unsigned short u16;
typedef unsigned int u32;

// ---------------- constants ----------------
#define BATCH 2
#define NSEQ  4096
#define DIM   1024
#define HEADS 16
#define DH    64
#define WIN   512
#define INNER 2730
#define ROWS  8192
#define QKV_N 3072
#define FF1_N 5460
#define FF1_NP 5632      // padded N for ff1 (22*256)
#define INNER_P 2816     // padded K for ff2 (88*32)
#define KROT 0.28782313663f   // ln(10000)/32

typedef __attribute__((ext_vector_type(8))) short short8;
typedef __attribute__((ext_vector_type(4))) float float4v;

__device__ __forceinline__ float bf2f(u16 u){ union{u32 i;float f;}c; c.i=((u32)u)<<16; return c.f; }
__device__ __forceinline__ u16 f2bf(float f){ union{float f;u32 i;}c; c.f=f; u32 i=c.i;
    return (u16)((i + 0x7FFFu + ((i>>16)&1u))>>16); }

// fast GELU (tanh form via hw exp): |err vs exact| <= ~3e-3, fine at 0.109 threshold
__device__ __forceinline__ float gelu_fast(float g) {
    float t = 0.7978845608f * (g + 0.044715f * g * g * g);
    float th = 1.f - 2.f / (1.f + __expf(2.f * t));
    return 0.5f * g * (1.f + th);
}

// async global->LDS, 16B per lane. LDS dest = wave-uniform base + lane*16; global src may scatter per lane.
__device__ __forceinline__ void gl_lds16(const u16* g, const u16* ldsbase) {
    __builtin_amdgcn_global_load_lds(
        (const __attribute__((address_space(1))) u32*)(uintptr_t)g,
        (__attribute__((address_space(3))) u32*)(uintptr_t)ldsbase,
        16, 0, 0);
}

// ff1 interleave mapping: output row n' of wf1t -> source column of w_ff1
__device__ __forceinline__ int ff1_src(int n, bool& ok) {
    int t = n >> 7, m = n & 127, j = m >> 4, l = m & 15;
    int p = t * 64 + ((j >> 1) << 4) + l;
    ok = (p < INNER);
    return (j & 1) ? (INNER + p) : p;
}

// ---------------- weight transpose + cast: wt[n][k] = bf16(w[k][src(n)]), zero-padded ----------------
template <bool REMAP>
__global__ __launch_bounds__(256) void wtrans_kernel(const float* __restrict__ w, u16* __restrict__ wt,
                                                     int K0, int N0, int K1, int N1) {
    __shared__ float tile[32][33];
    int kt = blockIdx.x, nt = blockIdx.y;
    int tx = threadIdx.x & 31, ty = threadIdx.x >> 5;
    int nl = nt * 32 + tx;
    bool ok = (nl < N1);
    int sc = nl;
    if (REMAP) { bool v; sc = ff1_src(nl < N1 ? nl : 0, v); ok = ok && v; }
    else ok = ok && (nl < N0);
#pragma unroll
    for (int yy = 0; yy < 4; yy++) {
        int k = kt*32 + ty + yy*8;
        tile[ty+yy*8][tx] = (k < K0 && ok) ? w[(size_t)k*N0 + sc] : 0.f;
    }
    __syncthreads();
#pragma unroll
    for (int yy = 0; yy < 4; yy++) {
        int n = nt*32 + ty + yy*8, k = kt*32 + tx;
        if (n < N1 && k < K1) wt[(size_t)n*K1 + k] = f2bf(tile[tx][ty+yy*8]);
    }
}

// ---------------- LayerNorm: fp32 in, bf16 out (dim = 1024) ----------------
__global__ __launch_bounds__(256) void ln_kernel(const float* __restrict__ x,
                                                 const float* __restrict__ w,
                                                 const float* __restrict__ b,
                                                 u16* __restrict__ out) {
    int row = blockIdx.x;
    const float* xr = x + (size_t)row * DIM;
    int t = threadIdx.x;
    float v[4];
    float s = 0.f, s2 = 0.f;
#pragma unroll
    for (int i = 0; i < 4; i++) {
        float f = xr[t + 256 * i];
        v[i] = f; s += f; s2 += f * f;
    }
#pragma unroll
    for (int off = 32; off; off >>= 1) { s += __shfl_xor(s, off); s2 += __shfl_xor(s2, off); }
    __shared__ float ls[10];
    int wave = t >> 6, lane = t & 63;
    if (lane == 0) { ls[wave] = s; ls[4 + wave] = s2; }
    __syncthreads();
    if (t == 0) {
        float ts  = ls[0] + ls[1] + ls[2] + ls[3];
        float ts2 = ls[4] + ls[5] + ls[6] + ls[7];
        float mean = ts * (1.f / DIM);
        float var  = ts2 * (1.f / DIM) - mean * mean;
        ls[8] = mean; ls[9] = 1.f / sqrtf(var + 1e-5f);
    }
    __syncthreads();
    float mean = ls[8], inv = ls[9];
    u16* orow = out + (size_t)row * DIM;
#pragma unroll
    for (int i = 0; i < 4; i++) {
        int c = t + 256 * i;
        float y = (v[i] - mean) * inv * w[c];
        if (b) y += b[c];
        orow[c] = f2bf(y);
    }
}

// ---------------- 256x256 GEMM, BK=32, 4-deep ring, counted vmcnt ----------------
// MODE 2: bf16 out + rotary/scale (qkv).  MODE 3: bf16 GEGLU out (ff1, interleaved wf1t).
// PHASED=0: R2-exact coarse loop (1 barrier + 1 vmcnt per K-step) -- control.
// PHASED=1: 2 phases of 16 MFMA per step, 1 mid barrier, stage inside phases, no
//           manual lgkm drains / sched pins (compiler keeps fine-grained waits),
//           vmcnt folded into the step-end barrier.
template <int MODE, int PHASED>
__global__ __launch_bounds__(512, 2) void gemm256(const u16* __restrict__ A,
                                                  const u16* __restrict__ Bt,
                                                  void* __restrict__ Cv,
                                                  int N, int K) {
    extern __shared__ u16 lds[];
    u16* Asm = lds;             // [4][256*32]
    u16* Bsm = lds + 4 * 8192;  // [4][256*32]
    int tiles_n = N >> 8;
    int gs  = tiles_n << 3;
    int gid = blockIdx.x / gs;
    int loc = blockIdx.x % gs;
    int tm = gid * 8 + (loc & 7);
    int tn = loc >> 3;
    int tid = threadIdx.x, wave = tid >> 6, lane = tid & 63;
    int quad = lane >> 4, l15 = lane & 15;
    int wm = wave >> 2, wn = wave & 3;
    int srow = wave * 16 + (lane >> 2);                 // staging row within 128-row half
    int sgrp = (lane & 3) ^ ((srow >> 1) & 3);          // swizzled source 16B group
    const u16* Ag = A  + (size_t)(tm * 256 + srow) * K + sgrp * 8;
    const u16* Bg = Bt + (size_t)(tn * 256 + srow) * K + sgrp * 8;
    u16* Asw = Asm + wave * 512;                        // wave's linear LDS dest (1024B)
    u16* Bsw = Bsm + wave * 512;
    int rg = (l15 >> 1) & 3;                            // reader swizzle term
    int nk = K >> 5;

    float4v acc[8][4];
#pragma unroll
    for (int i = 0; i < 8; i++)
#pragma unroll
        for (int j = 0; j < 4; j++) acc[i][j] = (float4v){0.f, 0.f, 0.f, 0.f};

    auto stage2 = [&](int t, int h) {
        int b = t & 3;
        int k0 = t << 5;
        if (h == 0) {
            gl_lds16(Ag + k0,                   Asw + b * 8192);
            gl_lds16(Ag + (size_t)128 * K + k0, Asw + b * 8192 + 4096);
        } else {
            gl_lds16(Bg + k0,                   Bsw + b * 8192);
            gl_lds16(Bg + (size_t)128 * K + k0, Bsw + b * 8192 + 4096);
        }
    };
    auto ldsA = [&](int t, int i) -> short8 {
        const u16* Ab = Asm + (t & 3) * 8192;
        return *(const short8*)&Ab[(wm*128 + i*16 + l15) * 32 + ((quad ^ rg) * 8)];
    };
    auto ldsB = [&](int t, int j) -> short8 {
        const u16* Bb = Bsm + (t & 3) * 8192;
        return *(const short8*)&Bb[(wn*64 + j*16 + l15) * 32 + ((quad ^ rg) * 8)];
    };

    // prologue: 3 tiles in flight (12 loads), wait for tile 0 (8 newest = tiles 1,2 remain)
    stage2(0, 0); stage2(0, 1);
    stage2(1, 0); stage2(1, 1);
    stage2(2, 0); stage2(2, 1);

    if (PHASED == 0) {
        // ---- R2-exact control loop ----
        auto compute = [&](int t) {
            short8 af[8], bfr[4];
#pragma unroll
            for (int i = 0; i < 8; i++) af[i] = ldsA(t, i);
#pragma unroll
            for (int j = 0; j < 4; j++) bfr[j] = ldsB(t, j);
            __builtin_amdgcn_s_setprio(1);
#pragma unroll
            for (int i = 0; i < 8; i++)
#pragma unroll
                for (int j = 0; j < 4; j++)
                    acc[i][j] = __builtin_amdgcn_mfma_f32_16x16x32_bf16(af[i], bfr[j], acc[i][j], 0, 0, 0);
            __builtin_amdgcn_s_setprio(0);
        };
#define KSTEP(T, VM) \
        asm volatile("s_waitcnt vmcnt(" #VM ")" ::: "memory"); \
        __builtin_amdgcn_s_barrier(); \
        __builtin_amdgcn_sched_barrier(0); \
        compute(T); \
        if ((T) + 3 < nk) { stage2((T) + 3, 0); stage2((T) + 3, 1); }
        for (int t = 0; t < nk - 2; ++t) { KSTEP(t, 8); }
        { KSTEP(nk - 2, 4); }
        { KSTEP(nk - 1, 0); }
#undef KSTEP
    } else {
        // ---- 2-phase experimental loop ----
        asm volatile("s_waitcnt vmcnt(8)" ::: "memory");
        __builtin_amdgcn_s_barrier();
        for (int t = 0; t < nk; ++t) {
            short8 af[8], bfr[4];
            // phase A: 8 ds_read + A-half stage + 16 MFMA
#pragma unroll
            for (int i = 0; i < 4; i++) af[i] = ldsA(t, i);
#pragma unroll
            for (int j = 0; j < 4; j++) bfr[j] = ldsB(t, j);
            if (t + 3 < nk) stage2(t + 3, 0);
            __builtin_amdgcn_s_setprio(1);
#pragma unroll
            for (int i = 0; i < 4; i++)
#pragma unroll
                for (int j = 0; j < 4; j++)
                    acc[i][j] = __builtin_amdgcn_mfma_f32_16x16x32_bf16(af[i], bfr[j], acc[i][j], 0, 0, 0);
            __builtin_amdgcn_s_setprio(0);
            __builtin_amdgcn_s_barrier();
            // phase B: 4 ds_read + B-half stage + 16 MFMA
#pragma unroll
            for (int i = 4; i < 8; i++) af[i] = ldsA(t, i);
            if (t + 3 < nk) stage2(t + 3, 1);
            __builtin_amdgcn_s_setprio(1);
#pragma unroll
            for (int i = 4; i < 8; i++)
#pragma unroll
                for (int j = 0; j < 4; j++)
                    acc[i][j] = __builtin_amdgcn_mfma_f32_16x16x32_bf16(af[i], bfr[j], acc[i][j], 0, 0, 0);
            __builtin_amdgcn_s_setprio(0);
            // step boundary: tile t+1 must be resident before next step's reads
            if (t < nk - 1) {
                if (t < nk - 3)       asm volatile("s_waitcnt vmcnt(8)" ::: "memory");
                else if (t == nk - 3) asm volatile("s_waitcnt vmcnt(4)" ::: "memory");
                else                  asm volatile("s_waitcnt vmcnt(0)" ::: "memory");
                __builtin_amdgcn_s_barrier();
            }
        }
    }

    // ---------------- epilogues ----------------
    if (MODE == 2) {
        u16* C = (u16*)Cv;
        int sector = tn >> 2;                       // 0=q,1=k,2=v (256-col tiles, 4 per 1024)
        if (sector < 2) {
            float inv0 = __expf(-(float)l15 * KROT);
            float inv1 = __expf(-(float)(l15 + 16) * KROT);
            float sc = (sector == 0) ? 0.125f : 1.0f;
#pragma unroll
            for (int i = 0; i < 8; i++) {
#pragma unroll
                for (int r = 0; r < 4; r++) {
                    int row = tm*256 + wm*128 + i*16 + quad*4 + r;
                    float fn = (float)(row & (NSEQ - 1));
                    float s0, c0, s1, c1;
                    __sincosf(fn * inv0, &s0, &c0);
                    __sincosf(fn * inv1, &s1, &c1);
                    float a0 = acc[i][0][r], a1 = acc[i][1][r];
                    float a2 = acc[i][2][r], a3 = acc[i][3][r];
                    size_t base = (size_t)row * N + tn*256 + wn*64 + l15;
                    C[base]      = f2bf((a0*c0 - a2*s0) * sc);
                    C[base + 16] = f2bf((a1*c1 - a3*s1) * sc);
                    C[base + 32] = f2bf((a2*c0 + a0*s0) * sc);
                    C[base + 48] = f2bf((a3*c1 + a1*s1) * sc);
                }
            }
        } else {
#pragma unroll
            for (int i = 0; i < 8; i++)
#pragma unroll
                for (int r = 0; r < 4; r++) {
                    size_t base = (size_t)(tm*256 + wm*128 + i*16 + quad*4 + r) * N + tn*256 + wn*64 + l15;
#pragma unroll
                    for (int j = 0; j < 4; j++) C[base + j*16] = f2bf(acc[i][j][r]);
                }
        }
        return;
    }
    if (MODE == 3) {
        u16* ag = (u16*)Cv;
        int t128 = tn * 2 + (wn >> 1);              // 128-col block index in C
        int cb = t128 * 64 + (wn & 1) * 32;         // output col base in ag
#pragma unroll
        for (int i = 0; i < 8; i++) {
#pragma unroll
            for (int r = 0; r < 4; r++) {
                size_t row = (size_t)(tm*256 + wm*128 + i*16 + quad*4 + r);
#pragma unroll
                for (int jp = 0; jp < 2; jp++) {
                    float a = acc[i][2*jp][r];
                    float g = acc[i][2*jp+1][r];
                    int col = cb + jp*16 + l15;
                    ag[row * INNER_P + col] = f2bf(a * gelu_fast(g));
                }
            }
        }
        return;
    }
}

// ---------------- 256x128 GEMM, ring-3, fp32 out + resid (w_out, ff2) ----------------
// 256 threads (4 waves 2Mx2N), per-wave 128x64 (same frag layout as gemm256).
// LDS 72KB (3 slots x [A 256x32 | B 128x32]) -> 2 blocks/CU. Grid exactly 256 blocks,
// XCD-clustered: xcd x owns tm in [x*4, x*4+4) so A-panels stay in one XCD's L2.
__global__ __launch_bounds__(256, 2) void gemm_mn128(const u16* __restrict__ A,
                                                     const u16* __restrict__ Bt,
                                                     const float* __restrict__ resid,
                                                     float* __restrict__ C,
                                                     int N, int K) {
    extern __shared__ u16 lds[];
    int x = blockIdx.x & 7, s5 = blockIdx.x >> 3;
    int tm = x * 4 + (s5 & 3);
    int tn = s5 >> 2;
    int tid = threadIdx.x, wave = tid >> 6, lane = tid & 63;
    int quad = lane >> 4, l15 = lane & 15;
    int wm = wave >> 1, wn = wave & 1;
    int rg = (l15 >> 1) & 3;
    int srA = wave * 64 + (lane >> 2);          // + q*16
    int srB = wave * 32 + (lane >> 2);          // + q*16
    const u16* AgB = A  + (size_t)(tm * 256) * K;
    const u16* BgB = Bt + (size_t)(tn * 128) * K;
    int nk = K >> 5;

    float4v acc[8][4];
#pragma unroll
    for (int i = 0; i < 8; i++)
#pragma unroll
        for (int j = 0; j < 4; j++) acc[i][j] = (float4v){0.f, 0.f, 0.f, 0.f};

    auto stage = [&](int t) {
        int s = t % 3;
        int k0 = t << 5;
        u16* As = lds + s * 12288;
        u16* Bs = lds + s * 12288 + 8192;
#pragma unroll
        for (int q = 0; q < 4; q++) {
            int row = srA + q * 16;
            int g = (lane & 3) ^ ((row >> 1) & 3);
            gl_lds16(AgB + (size_t)row * K + k0 + g * 8, As + wave * 2048 + q * 512);
        }
#pragma unroll
        for (int q = 0; q < 2; q++) {
            int row = srB + q * 16;
            int g = (lane & 3) ^ ((row >> 1) & 3);
            gl_lds16(BgB + (size_t)row * K + k0 + g * 8, Bs + wave * 1024 + q * 512);
        }
    };

    stage(0); stage(1);
    for (int t = 0; t < nk; ++t) {
        if (t < nk - 1) asm volatile("s_waitcnt vmcnt(6)" ::: "memory");
        else            asm volatile("s_waitcnt vmcnt(0)" ::: "memory");
        __builtin_amdgcn_s_barrier();
        __builtin_amdgcn_sched_barrier(0);
        {
            int s = t % 3;
            const u16* As = lds + s * 12288;
            const u16* Bs = lds + s * 12288 + 8192;
            short8 af[8], bfr[4];
#pragma unroll
            for (int i = 0; i < 8; i++)
                af[i] = *(const short8*)&As[(wm*128 + i*16 + l15) * 32 + ((quad ^ rg) * 8)];
#pragma unroll
            for (int j = 0; j < 4; j++)
                bfr[j] = *(const short8*)&Bs[(wn*64 + j*16 + l15) * 32 + ((quad ^ rg) * 8)];
            __builtin_amdgcn_s_setprio(1);
#pragma unroll
            for (int i = 0; i < 8; i++)
#pragma unroll
                for (int j = 0; j < 4; j++)
                    acc[i][j] = __builtin_amdgcn_mfma_f32_16x16x32_bf16(af[i], bfr[j], acc[i][j], 0, 0, 0);
            __builtin_amdgcn_s_setprio(0);
        }
        if (t + 2 < nk) stage(t + 2);
    }

#pragma unroll
    for (int i = 0; i < 8; i++) {
#pragma unroll
        for (int r = 0; r < 4; r++) {
            size_t row = (size_t)(tm*256 + wm*128 + i*16 + quad*4 + r);
#pragma unroll
            for (int j = 0; j < 4; j++) {
                int col = tn*128 + wn*64 + j*16 + l15;
                size_t idx = row * N + col;
                C[idx] = acc[i][j][r] + resid[idx];
            }
        }
    }
}

// ---------------- V transpose: vt[b][h][d][n] = qkv.v[b,n,h,d] ----------------
__global__ __launch_bounds__(256) void vtrans_kernel(const u16* __restrict__ qkv, u16* __restrict__ vt) {
    __shared__ u16 tile[64][72];
    int t = threadIdx.x;
    int n0 = (blockIdx.x & 63) * 64;
    int hh = (blockIdx.x >> 6) & 15;
    int b  = blockIdx.x >> 10;
    int r = t >> 2, cb = (t & 3) * 16;
    const u16* src = qkv + (size_t)(b * NSEQ + n0 + r) * QKV_N + 2 * DIM + hh * 64 + cb;
    uint4 v0 = *(const uint4*)(src);
    uint4 v1 = *(const uint4*)(src + 8);
    *(uint4*)&tile[r][cb]     = v0;
    *(uint4*)&tile[r][cb + 8] = v1;
    __syncthreads();
    int d = t >> 2, nb = (t & 3) * 16;
    __align__(16) u16 vals[16];
#pragma unroll
    for (int e = 0; e < 16; e++) vals[e] = tile[nb + e][d];
    u16* dst = vt + ((size_t)(b * HEADS + hh) * DH + d) * NSEQ + n0 + nb;
    *(uint4*)(dst)     = *(uint4*)&vals[0];
    *(uint4*)(dst + 8) = *(uint4*)&vals[8];
}

// ---------------- MFMA flash attention, block-cooperative LDS staging ----------------
__global__ __launch_bounds__(256) void attn_kernel(const u16* __restrict__ qkv,
                                                   const u16* __restrict__ vt,
                                                   u16* __restrict__ o) {
    __shared__ u16 Ks[128 * 64];
    __shared__ u16 Vs[64 * 128];
    __shared__ u16 p_lds[4][16][136];
    int tid = threadIdx.x, wave = tid >> 6, lane = tid & 63;
    int quad = lane >> 4, l15 = lane & 15;
    int bi = blockIdx.x;
    int qb = bi & 7, w0 = (bi >> 3) & 7, hh = (bi >> 6) & 15, b = bi >> 10;
    int qt = qb * 4 + wave;
    int qlocal = qt * 16 + l15;
    const u16* qp = qkv + (size_t)(b*NSEQ + w0*WIN + qt*16 + l15) * QKV_N + hh*64 + quad*8;
    short8 bq0 = *(const short8*)(qp);
    short8 bq1 = *(const short8*)(qp + 32);
    int krow0 = b * NSEQ + (w0 - 1) * WIN;
    const u16* vbase = vt + (size_t)(b * HEADS + hh) * DH * NSEQ + (w0 - 1) * WIN;
    int ks_row = lane >> 3;
    int ks_g   = (lane & 7) ^ ks_row;
    int vs_row = lane >> 4;
    int vs_j0  = lane & 15;
    int swz = l15 & 7;
    float m_ = -1e30f, l_ = 0.f;
    float4v O[4] = {{0,0,0,0},{0,0,0,0},{0,0,0,0},{0,0,0,0}};
    int cstart = (w0 == 0) ? 4 : 0;
    int clast  = (512 + qb * 64 + 63) >> 7;
    u16 (*pt)[136] = p_lds[wave];
    for (int c = cstart; c <= clast; c++) {
        int kb = c * 128;
        __syncthreads();
#pragma unroll
        for (int i = 0; i < 4; i++) {
            int kloc = wave * 32 + i * 8 + ks_row;
            gl_lds16(qkv + (size_t)(krow0 + kb + kloc) * QKV_N + DIM + hh*64 + ks_g*8,
                     &Ks[(wave*32 + i*8) * 64]);
        }
#pragma unroll
        for (int i = 0; i < 4; i++) {
            int dloc = wave * 16 + i * 4 + vs_row;
            int jsrc = vs_j0 ^ (dloc & 7);
            gl_lds16(vbase + (size_t)dloc * NSEQ + kb + jsrc * 8,
                     &Vs[(wave*16 + i*4) * 128]);
        }
        __syncthreads();
        float4v s[8];
#pragma unroll
        for (int t = 0; t < 8; t++) {
            int krow = (t*16 + l15) * 64;
            short8 ka0 = *(const short8*)&Ks[krow + ((quad    ) ^ swz) * 8];
            short8 ka1 = *(const short8*)&Ks[krow + ((quad + 4) ^ swz) * 8];
            float4v st = {0.f, 0.f, 0.f, 0.f};
            st = __builtin_amdgcn_mfma_f32_16x16x32_bf16(ka0, bq0, st, 0, 0, 0);
            st = __builtin_amdgcn_mfma_f32_16x16x32_bf16(ka1, bq1, st, 0, 0, 0);
            int ck = kb + t*16 + quad*4;
#pragma unroll
            for (int r = 0; r < 4; r++)
                if (ck + r >= 512 && ck + r - 512 > qlocal) st[r] = -1e30f;
            s[t] = st;
        }
        float mc = -1e30f;
#pragma unroll
        for (int t = 0; t < 8; t++)
#pragma unroll
            for (int r = 0; r < 4; r++) mc = fmaxf(mc, s[t][r]);
        mc = fmaxf(mc, __shfl_xor(mc, 16));
        mc = fmaxf(mc, __shfl_xor(mc, 32));
        float mn = fmaxf(m_, mc);
        float alpha = __expf(m_ - mn);
        m_ = mn;
        float su = 0.f;
#pragma unroll
        for (int t = 0; t < 8; t++) {
            union { u16 h[4]; uint2 v; } pk;
#pragma unroll
            for (int r = 0; r < 4; r++) {
                float p = __expf(s[t][r] - mn);
                su += p;
                pk.h[r] = f2bf(p);
            }
            *(uint2*)&pt[l15][t*16 + quad*4] = pk.v;
        }
        su += __shfl_xor(su, 16);
        su += __shfl_xor(su, 32);
        l_ = l_ * alpha + su;
#pragma unroll
        for (int t = 0; t < 4; t++)
#pragma unroll
            for (int r = 0; r < 4; r++) O[t][r] *= alpha;
#pragma unroll
        for (int g = 0; g < 4; g++) {
            short8 pf = *(const short8*)&pt[l15][g*32 + quad*8];
#pragma unroll
            for (int t = 0; t < 4; t++) {
                short8 vf = *(const short8*)&Vs[(t*16 + l15) * 128 + ((g*4 + quad) ^ swz) * 8];
                O[t] = __builtin_amdgcn_mfma_f32_16x16x32_bf16(vf, pf, O[t], 0, 0, 0);
            }
        }
    }
    float inv = 1.f / l_;
    u16* op = o + (size_t)(b*NSEQ + w0*WIN + qt*16 + l15) * DIM + hh*64;
#pragma unroll
    for (int t = 0; t < 4; t++) {
        union { u16 h[4]; uint2 v; } pk;
#pragma unroll
        for (int r = 0; r < 4; r++) pk.h[r] = f2bf(O[t][r] * inv);
        *(uint2*)(op + t*16 + quad*4) = pk.v;
    }
}

// ---------------- launch ----------------
extern "C" void kernel_launch(void* const* d_in, const int* in_sizes, int n_in,
                              void* d_out, int out_size, void* d_ws, size_t ws_size,
                              hipStream_t stream) {
    const float* x      = (const float*)d_in[0];
    const float* ln1_w  = (const float*)d_in[1];
    const float* ln1_b  = (const float*)d_in[2];
    const float* w_qkv  = (const float*)d_in[3];
    const float* w_out  = (const float*)d_in[4];
    const float* ln2_w  = (const float*)d_in[5];
    const float* w_ff1  = (const float*)d_in[6];
    const float* w_ff2  = (const float*)d_in[7];
    float* out = (float*)d_out;

    static bool cfg = false;
    if (!cfg) {
        hipFuncSetAttribute((const void*)gemm256<2, 0>, hipFuncAttributeMaxDynamicSharedMemorySize, 131072);
        hipFuncSetAttribute((const void*)gemm256<3, 1>, hipFuncAttributeMaxDynamicSharedMemorySize, 131072);
        hipFuncSetAttribute((const void*)gemm_mn128,    hipFuncAttributeMaxDynamicSharedMemorySize, 73728);
        cfg = true;
    }

    char* ws = (char*)d_ws;
    size_t off = 0;
    auto alloc = [&](size_t bytes) { size_t o = off; off += (bytes + 255) & ~(size_t)255; return o; };
    size_t off_wqt  = alloc((size_t)QKV_N  * DIM * 2);
    size_t off_wot  = alloc((size_t)DIM    * DIM * 2);
    size_t off_wf1t = alloc((size_t)FF1_NP * DIM * 2);
    size_t off_wf2t = alloc((size_t)DIM    * INNER_P * 2);
    size_t off_h    = alloc((size_t)ROWS * DIM * 2);
    size_t sz_qkv = (size_t)ROWS * QKV_N * 2;
    size_t sz_vt  = (size_t)BATCH * HEADS * DH * NSEQ * 2;
    size_t off_qkv  = alloc(sz_qkv);
    size_t off_vt   = alloc(sz_vt);
    size_t off_o    = alloc((size_t)ROWS * DIM * 2);
    size_t off_x1   = alloc((size_t)ROWS * DIM * 4);
    size_t off_ag   = alloc((size_t)ROWS * INNER_P * 2);

    u16* wqt  = (u16*)(ws + off_wqt);
    u16* wot  = (u16*)(ws + off_wot);
    u16* wf1t = (u16*)(ws + off_wf1t);
    u16* wf2t = (u16*)(ws + off_wf2t);
    u16* h    = (u16*)(ws + off_h);
    u16* qkv  = (u16*)(ws + off_qkv);
    u16* vt   = (u16*)(ws + off_vt);
    u16* o    = (u16*)(ws + off_o);
    float* x1 = (float*)(ws + off_x1);
    u16* ag   = (u16*)(ws + off_ag);

    // 0) transpose+cast weights -> bf16 [N][K]; ff1 column-interleaved (a,g) pairs
    wtrans_kernel<false><<<dim3(32, 96),  256, 0, stream>>>(w_qkv, wqt,  DIM,   QKV_N, DIM,     QKV_N);
    wtrans_kernel<false><<<dim3(32, 32),  256, 0, stream>>>(w_out, wot,  DIM,   DIM,   DIM,     DIM);
    wtrans_kernel<true ><<<dim3(32, 176), 256, 0, stream>>>(w_ff1, wf1t, DIM,   FF1_N, DIM,     FF1_NP);
    wtrans_kernel<false><<<dim3(88, 32),  256, 0, stream>>>(w_ff2, wf2t, INNER, DIM,   INNER_P, DIM);

    // 1) LN1
    ln_kernel<<<ROWS, 256, 0, stream>>>(x, ln1_w, ln1_b, h);
    // 2) qkv = h @ w_qkv, rotary+scale fused (256^2 ring kernel, R2 control schedule)
    gemm256<2, 0><<<(ROWS/256) * (QKV_N/256), 512, 131072, stream>>>(h, wqt, qkv, QKV_N, DIM);
    // 3) V transpose
    vtrans_kernel<<<BATCH * HEADS * (NSEQ / 64), 256, 0, stream>>>(qkv, vt);
    // 4) attention
    attn_kernel<<<BATCH * HEADS * 8 * 8, 256, 0, stream>>>(qkv, vt, o);
    // 5) x1 = o @ w_out + x  (256x128 ring-3, 2 blocks/CU)
    gemm_mn128<<<256, 256, 73728, stream>>>(o, wot, x, x1, DIM, DIM);
    // 6) h2 = LN2(x1)
    ln_kernel<<<ROWS, 256, 0, stream>>>(x1, ln2_w, nullptr, h);
    // 7) ag = geglu(h2 @ w_ff1) fused, writes [8192 x 2816] (256^2 ring kernel, 2-phase experiment)
    gemm256<3, 1><<<(ROWS/256) * (FF1_NP/256), 512, 131072, stream>>>(h, wf1t, ag, FF1_NP, DIM);
    // 8) out = ag @ w_ff2 + x1  (256x128 ring-3, 2 blocks/CU)
    gemm_mn128<<<256, 256, 73728, stream>>>(ag, wf2t, x1, out, DIM, INNER_P);

    (void)in_sizes; (void)n_in; (void)out_size; (void)ws_size;
}

// Round 5
// 510.503 us; speedup vs baseline: 1.0655x; 1.0330x over previous
//
#include <hip/hip_runtime.h>
#include <stdint.h>

typedef unsigned short u16;
typedef unsigned int u32;

// ---------------- constants ----------------
#define BATCH 2
#define NSEQ  4096
#define DIM   1024
#define HEADS 16
#define DH    64
#define WIN   512
#define INNER 2730
#define ROWS  8192
#define QKV_N 3072
#define FF1_N 5460
#define FF1_NP 5632      // padded N for ff1 (22*256)
#define INNER_P 2816     // padded K for ff2 (88*32)
#define KROT 0.28782313663f   // ln(10000)/32

typedef __attribute__((ext_vector_type(8))) short short8;
typedef __attribute__((ext_vector_type(4))) float float4v;

__device__ __forceinline__ float bf2f(u16 u){ union{u32 i;float f;}c; c.i=((u32)u)<<16; return c.f; }
__device__ __forceinline__ u16 f2bf(float f){ union{float f;u32 i;}c; c.f=f; u32 i=c.i;
    return (u16)((i + 0x7FFFu + ((i>>16)&1u))>>16); }

// fast GELU (tanh form via hw exp): |err vs exact| <= ~3e-3, fine at 0.109 threshold
__device__ __forceinline__ float gelu_fast(float g) {
    float t = 0.7978845608f * (g + 0.044715f * g * g * g);
    float th = 1.f - 2.f / (1.f + __expf(2.f * t));
    return 0.5f * g * (1.f + th);
}

// async global->LDS, 16B per lane. LDS dest = wave-uniform base + lane*16; global src may scatter per lane.
__device__ __forceinline__ void gl_lds16(const u16* g, const u16* ldsbase) {
    __builtin_amdgcn_global_load_lds(
        (const __attribute__((address_space(1))) u32*)(uintptr_t)g,
        (__attribute__((address_space(3))) u32*)(uintptr_t)ldsbase,
        16, 0, 0);
}

// ff1 interleave mapping: output row n' of wf1t -> source column of w_ff1
__device__ __forceinline__ int ff1_src(int n, bool& ok) {
    int t = n >> 7, m = n & 127, j = m >> 4, l = m & 15;
    int p = t * 64 + ((j >> 1) << 4) + l;
    ok = (p < INNER);
    return (j & 1) ? (INNER + p) : p;
}

// ---------------- weight transpose + cast: wt[n][k] = bf16(w[k][src(n)]), zero-padded ----------------
template <bool REMAP>
__global__ __launch_bounds__(256) void wtrans_kernel(const float* __restrict__ w, u16* __restrict__ wt,
                                                     int K0, int N0, int K1, int N1) {
    __shared__ float tile[32][33];
    int kt = blockIdx.x, nt = blockIdx.y;
    int tx = threadIdx.x & 31, ty = threadIdx.x >> 5;
    int nl = nt * 32 + tx;
    bool ok = (nl < N1);
    int sc = nl;
    if (REMAP) { bool v; sc = ff1_src(nl < N1 ? nl : 0, v); ok = ok && v; }
    else ok = ok && (nl < N0);
#pragma unroll
    for (int yy = 0; yy < 4; yy++) {
        int k = kt*32 + ty + yy*8;
        tile[ty+yy*8][tx] = (k < K0 && ok) ? w[(size_t)k*N0 + sc] : 0.f;
    }
    __syncthreads();
#pragma unroll
    for (int yy = 0; yy < 4; yy++) {
        int n = nt*32 + ty + yy*8, k = kt*32 + tx;
        if (n < N1 && k < K1) wt[(size_t)n*K1 + k] = f2bf(tile[tx][ty+yy*8]);
    }
}

// ---------------- LayerNorm: fp32 in, bf16 out (dim = 1024) ----------------
__global__ __launch_bounds__(256) void ln_kernel(const float* __restrict__ x,
                                                 const float* __restrict__ w,
                                                 const float* __restrict__ b,
                                                 u16* __restrict__ out) {
    int row = blockIdx.x;
    const float* xr = x + (size_t)row * DIM;
    int t = threadIdx.x;
    float v[4];
    float s = 0.f, s2 = 0.f;
#pragma unroll
    for (int i = 0; i < 4; i++) {
        float f = xr[t + 256 * i];
        v[i] = f; s += f; s2 += f * f;
    }
#pragma unroll
    for (int off = 32; off; off >>= 1) { s += __shfl_xor(s, off); s2 += __shfl_xor(s2, off); }
    __shared__ float ls[10];
    int wave = t >> 6, lane = t & 63;
    if (lane == 0) { ls[wave] = s; ls[4 + wave] = s2; }
    __syncthreads();
    if (t == 0) {
        float ts  = ls[0] + ls[1] + ls[2] + ls[3];
        float ts2 = ls[4] + ls[5] + ls[6] + ls[7];
        float mean = ts * (1.f / DIM);
        float var  = ts2 * (1.f / DIM) - mean * mean;
        ls[8] = mean; ls[9] = 1.f / sqrtf(var + 1e-5f);
    }
    __syncthreads();
    float mean = ls[8], inv = ls[9];
    u16* orow = out + (size_t)row * DIM;
#pragma unroll
    for (int i = 0; i < 4; i++) {
        int c = t + 256 * i;
        float y = (v[i] - mean) * inv * w[c];
        if (b) y += b[c];
        orow[c] = f2bf(y);
    }
}

// ---------------- 128x256 GEMM, ring-3, 2 blocks/CU (qkv, ff1) ----------------
// 256 threads, 4 waves across N; per-wave 128x64 output (8x4 frags) -- same frag
// geometry/swizzle as the validated kernels. Coarse schedule (= mn128's proven loop):
// { vmcnt(6); barrier; ds_read 12 + 32 MFMA; stage(t+2) }.
// LDS: 3 slots x [A 128x32 | B 256x32] = 72 KiB -> 2 blocks/CU for cross-block overlap
// (epilogue/prologue of one block hides under the other's K-loop).
// MODE 2: bf16 out + rotary/scale (qkv).  MODE 3: bf16 GEGLU out (ff1, interleaved wf1t).
template <int MODE>
__global__ __launch_bounds__(256, 2) void gemm_k(const u16* __restrict__ A,
                                                 const u16* __restrict__ Bt,
                                                 void* __restrict__ Cv,
                                                 int N, int K) {
    extern __shared__ u16 lds[];
    int tiles_n = N >> 8;
    int gs  = tiles_n << 3;                 // supergroup: 8 m-tiles x all n-tiles
    int gid = blockIdx.x / gs;
    int loc = blockIdx.x % gs;
    int tm = gid * 8 + (loc & 7);
    int tn = loc >> 3;
    int tid = threadIdx.x, wave = tid >> 6, lane = tid & 63;
    int quad = lane >> 4, l15 = lane & 15;
    int wn = wave;
    int rg = (l15 >> 1) & 3;                // reader swizzle term
    int srA = wave * 32 + (lane >> 2);      // + q*16, q in 0..1 (A: 128 rows)
    int srB = wave * 64 + (lane >> 2);      // + q*16, q in 0..3 (B: 256 rows)
    const u16* AgB = A  + (size_t)(tm * 128) * K;
    const u16* BgB = Bt + (size_t)(tn * 256) * K;
    int nk = K >> 5;

    float4v acc[8][4];
#pragma unroll
    for (int i = 0; i < 8; i++)
#pragma unroll
        for (int j = 0; j < 4; j++) acc[i][j] = (float4v){0.f, 0.f, 0.f, 0.f};

    auto stage = [&](int t) {
        int s = t % 3;
        int k0 = t << 5;
        u16* As = lds + s * 12288;          // A slot: 128*32 u16
        u16* Bs = lds + s * 12288 + 4096;   // B slot: 256*32 u16
#pragma unroll
        for (int q = 0; q < 2; q++) {
            int row = srA + q * 16;
            int g = (lane & 3) ^ ((row >> 1) & 3);
            gl_lds16(AgB + (size_t)row * K + k0 + g * 8, As + wave * 1024 + q * 512);
        }
#pragma unroll
        for (int q = 0; q < 4; q++) {
            int row = srB + q * 16;
            int g = (lane & 3) ^ ((row >> 1) & 3);
            gl_lds16(BgB + (size_t)row * K + k0 + g * 8, Bs + wave * 2048 + q * 512);
        }
    };

    stage(0); stage(1);
    for (int t = 0; t < nk; ++t) {
        if (t < nk - 1) asm volatile("s_waitcnt vmcnt(6)" ::: "memory");
        else            asm volatile("s_waitcnt vmcnt(0)" ::: "memory");
        __builtin_amdgcn_s_barrier();
        __builtin_amdgcn_sched_barrier(0);
        {
            int s = t % 3;
            const u16* As = lds + s * 12288;
            const u16* Bs = lds + s * 12288 + 4096;
            short8 af[8], bfr[4];
#pragma unroll
            for (int i = 0; i < 8; i++)
                af[i] = *(const short8*)&As[(i*16 + l15) * 32 + ((quad ^ rg) * 8)];
#pragma unroll
            for (int j = 0; j < 4; j++)
                bfr[j] = *(const short8*)&Bs[(wn*64 + j*16 + l15) * 32 + ((quad ^ rg) * 8)];
            __builtin_amdgcn_s_setprio(1);
#pragma unroll
            for (int i = 0; i < 8; i++)
#pragma unroll
                for (int j = 0; j < 4; j++)
                    acc[i][j] = __builtin_amdgcn_mfma_f32_16x16x32_bf16(af[i], bfr[j], acc[i][j], 0, 0, 0);
            __builtin_amdgcn_s_setprio(0);
        }
        if (t + 2 < nk) stage(t + 2);
    }

    // ---------------- epilogues ----------------
    if (MODE == 2) {
        u16* C = (u16*)Cv;
        int sector = tn >> 2;                       // 0=q,1=k,2=v (256-col tiles, 4 per 1024)
        if (sector < 2) {
            float inv0 = __expf(-(float)l15 * KROT);
            float inv1 = __expf(-(float)(l15 + 16) * KROT);
            float sc = (sector == 0) ? 0.125f : 1.0f;
#pragma unroll
            for (int i = 0; i < 8; i++) {
#pragma unroll
                for (int r = 0; r < 4; r++) {
                    int row = tm*128 + i*16 + quad*4 + r;
                    float fn = (float)(row & (NSEQ - 1));
                    float s0, c0, s1, c1;
                    __sincosf(fn * inv0, &s0, &c0);
                    __sincosf(fn * inv1, &s1, &c1);
                    float a0 = acc[i][0][r], a1 = acc[i][1][r];
                    float a2 = acc[i][2][r], a3 = acc[i][3][r];
                    size_t base = (size_t)row * N + tn*256 + wn*64 + l15;
                    C[base]      = f2bf((a0*c0 - a2*s0) * sc);
                    C[base + 16] = f2bf((a1*c1 - a3*s1) * sc);
                    C[base + 32] = f2bf((a2*c0 + a0*s0) * sc);
                    C[base + 48] = f2bf((a3*c1 + a1*s1) * sc);
                }
            }
        } else {
#pragma unroll
            for (int i = 0; i < 8; i++)
#pragma unroll
                for (int r = 0; r < 4; r++) {
                    size_t base = (size_t)(tm*128 + i*16 + quad*4 + r) * N + tn*256 + wn*64 + l15;
#pragma unroll
                    for (int j = 0; j < 4; j++) C[base + j*16] = f2bf(acc[i][j][r]);
                }
        }
        return;
    }
    if (MODE == 3) {
        u16* ag = (u16*)Cv;
        int t128 = tn * 2 + (wn >> 1);              // 128-col block index in C
        int cb = t128 * 64 + (wn & 1) * 32;         // output col base in ag
#pragma unroll
        for (int i = 0; i < 8; i++) {
#pragma unroll
            for (int r = 0; r < 4; r++) {
                size_t row = (size_t)(tm*128 + i*16 + quad*4 + r);
#pragma unroll
                for (int jp = 0; jp < 2; jp++) {
                    float a = acc[i][2*jp][r];
                    float g = acc[i][2*jp+1][r];
                    int col = cb + jp*16 + l15;
                    ag[row * INNER_P + col] = f2bf(a * gelu_fast(g));
                }
            }
        }
        return;
    }
}

// ---------------- 256x128 GEMM, ring-3, fp32 out + resid (w_out, ff2) ----------------
// 256 threads (4 waves 2Mx2N), per-wave 128x64 (same frag layout as gemm_k).
// LDS 72KB (3 slots x [A 256x32 | B 128x32]) -> 2 blocks/CU. Grid exactly 256 blocks,
// XCD-clustered: xcd x owns tm in [x*4, x*4+4) so A-panels stay in one XCD's L2.
__global__ __launch_bounds__(256, 2) void gemm_mn128(const u16* __restrict__ A,
                                                     const u16* __restrict__ Bt,
                                                     const float* __restrict__ resid,
                                                     float* __restrict__ C,
                                                     int N, int K) {
    extern __shared__ u16 lds[];
    int x = blockIdx.x & 7, s5 = blockIdx.x >> 3;
    int tm = x * 4 + (s5 & 3);
    int tn = s5 >> 2;
    int tid = threadIdx.x, wave = tid >> 6, lane = tid & 63;
    int quad = lane >> 4, l15 = lane & 15;
    int wm = wave >> 1, wn = wave & 1;
    int rg = (l15 >> 1) & 3;
    int srA = wave * 64 + (lane >> 2);          // + q*16
    int srB = wave * 32 + (lane >> 2);          // + q*16
    const u16* AgB = A  + (size_t)(tm * 256) * K;
    const u16* BgB = Bt + (size_t)(tn * 128) * K;
    int nk = K >> 5;

    float4v acc[8][4];
#pragma unroll
    for (int i = 0; i < 8; i++)
#pragma unroll
        for (int j = 0; j < 4; j++) acc[i][j] = (float4v){0.f, 0.f, 0.f, 0.f};

    auto stage = [&](int t) {
        int s = t % 3;
        int k0 = t << 5;
        u16* As = lds + s * 12288;
        u16* Bs = lds + s * 12288 + 8192;
#pragma unroll
        for (int q = 0; q < 4; q++) {
            int row = srA + q * 16;
            int g = (lane & 3) ^ ((row >> 1) & 3);
            gl_lds16(AgB + (size_t)row * K + k0 + g * 8, As + wave * 2048 + q * 512);
        }
#pragma unroll
        for (int q = 0; q < 2; q++) {
            int row = srB + q * 16;
            int g = (lane & 3) ^ ((row >> 1) & 3);
            gl_lds16(BgB + (size_t)row * K + k0 + g * 8, Bs + wave * 1024 + q * 512);
        }
    };

    stage(0); stage(1);
    for (int t = 0; t < nk; ++t) {
        if (t < nk - 1) asm volatile("s_waitcnt vmcnt(6)" ::: "memory");
        else            asm volatile("s_waitcnt vmcnt(0)" ::: "memory");
        __builtin_amdgcn_s_barrier();
        __builtin_amdgcn_sched_barrier(0);
        {
            int s = t % 3;
            const u16* As = lds + s * 12288;
            const u16* Bs = lds + s * 12288 + 8192;
            short8 af[8], bfr[4];
#pragma unroll
            for (int i = 0; i < 8; i++)
                af[i] = *(const short8*)&As[(wm*128 + i*16 + l15) * 32 + ((quad ^ rg) * 8)];
#pragma unroll
            for (int j = 0; j < 4; j++)
                bfr[j] = *(const short8*)&Bs[(wn*64 + j*16 + l15) * 32 + ((quad ^ rg) * 8)];
            __builtin_amdgcn_s_setprio(1);
#pragma unroll
            for (int i = 0; i < 8; i++)
#pragma unroll
                for (int j = 0; j < 4; j++)
                    acc[i][j] = __builtin_amdgcn_mfma_f32_16x16x32_bf16(af[i], bfr[j], acc[i][j], 0, 0, 0);
            __builtin_amdgcn_s_setprio(0);
        }
        if (t + 2 < nk) stage(t + 2);
    }

#pragma unroll
    for (int i = 0; i < 8; i++) {
#pragma unroll
        for (int r = 0; r < 4; r++) {
            size_t row = (size_t)(tm*256 + wm*128 + i*16 + quad*4 + r);
#pragma unroll
            for (int j = 0; j < 4; j++) {
                int col = tn*128 + wn*64 + j*16 + l15;
                size_t idx = row * N + col;
                C[idx] = acc[i][j][r] + resid[idx];
            }
        }
    }
}

// ---------------- V transpose: vt[b][h][d][n] = qkv.v[b,n,h,d] ----------------
__global__ __launch_bounds__(256) void vtrans_kernel(const u16* __restrict__ qkv, u16* __restrict__ vt) {
    __shared__ u16 tile[64][72];
    int t = threadIdx.x;
    int n0 = (blockIdx.x & 63) * 64;
    int hh = (blockIdx.x >> 6) & 15;
    int b  = blockIdx.x >> 10;
    int r = t >> 2, cb = (t & 3) * 16;
    const u16* src = qkv + (size_t)(b * NSEQ + n0 + r) * QKV_N + 2 * DIM + hh * 64 + cb;
    uint4 v0 = *(const uint4*)(src);
    uint4 v1 = *(const uint4*)(src + 8);
    *(uint4*)&tile[r][cb]     = v0;
    *(uint4*)&tile[r][cb + 8] = v1;
    __syncthreads();
    int d = t >> 2, nb = (t & 3) * 16;
    __align__(16) u16 vals[16];
#pragma unroll
    for (int e = 0; e < 16; e++) vals[e] = tile[nb + e][d];
    u16* dst = vt + ((size_t)(b * HEADS + hh) * DH + d) * NSEQ + n0 + nb;
    *(uint4*)(dst)     = *(uint4*)&vals[0];
    *(uint4*)(dst + 8) = *(uint4*)&vals[8];
}

// ---------------- MFMA flash attention, block-cooperative LDS staging ----------------
__global__ __launch_bounds__(256) void attn_kernel(const u16* __restrict__ qkv,
                                                   const u16* __restrict__ vt,
                                                   u16* __restrict__ o) {
    __shared__ u16 Ks[128 * 64];
    __shared__ u16 Vs[64 * 128];
    __shared__ u16 p_lds[4][16][136];
    int tid = threadIdx.x, wave = tid >> 6, lane = tid & 63;
    int quad = lane >> 4, l15 = lane & 15;
    int bi = blockIdx.x;
    int qb = bi & 7, w0 = (bi >> 3) & 7, hh = (bi >> 6) & 15, b = bi >> 10;
    int qt = qb * 4 + wave;
    int qlocal = qt * 16 + l15;
    const u16* qp = qkv + (size_t)(b*NSEQ + w0*WIN + qt*16 + l15) * QKV_N + hh*64 + quad*8;
    short8 bq0 = *(const short8*)(qp);
    short8 bq1 = *(const short8*)(qp + 32);
    int krow0 = b * NSEQ + (w0 - 1) * WIN;
    const u16* vbase = vt + (size_t)(b * HEADS + hh) * DH * NSEQ + (w0 - 1) * WIN;
    int ks_row = lane >> 3;
    int ks_g   = (lane & 7) ^ ks_row;
    int vs_row = lane >> 4;
    int vs_j0  = lane & 15;
    int swz = l15 & 7;
    float m_ = -1e30f, l_ = 0.f;
    float4v O[4] = {{0,0,0,0},{0,0,0,0},{0,0,0,0},{0,0,0,0}};
    int cstart = (w0 == 0) ? 4 : 0;
    int clast  = (512 + qb * 64 + 63) >> 7;
    u16 (*pt)[136] = p_lds[wave];
    for (int c = cstart; c <= clast; c++) {
        int kb = c * 128;
        __syncthreads();
#pragma unroll
        for (int i = 0; i < 4; i++) {
            int kloc = wave * 32 + i * 8 + ks_row;
            gl_lds16(qkv + (size_t)(krow0 + kb + kloc) * QKV_N + DIM + hh*64 + ks_g*8,
                     &Ks[(wave*32 + i*8) * 64]);
        }
#pragma unroll
        for (int i = 0; i < 4; i++) {
            int dloc = wave * 16 + i * 4 + vs_row;
            int jsrc = vs_j0 ^ (dloc & 7);
            gl_lds16(vbase + (size_t)dloc * NSEQ + kb + jsrc * 8,
                     &Vs[(wave*16 + i*4) * 128]);
        }
        __syncthreads();
        float4v s[8];
#pragma unroll
        for (int t = 0; t < 8; t++) {
            int krow = (t*16 + l15) * 64;
            short8 ka0 = *(const short8*)&Ks[krow + ((quad    ) ^ swz) * 8];
            short8 ka1 = *(const short8*)&Ks[krow + ((quad + 4) ^ swz) * 8];
            float4v st = {0.f, 0.f, 0.f, 0.f};
            st = __builtin_amdgcn_mfma_f32_16x16x32_bf16(ka0, bq0, st, 0, 0, 0);
            st = __builtin_amdgcn_mfma_f32_16x16x32_bf16(ka1, bq1, st, 0, 0, 0);
            int ck = kb + t*16 + quad*4;
#pragma unroll
            for (int r = 0; r < 4; r++)
                if (ck + r >= 512 && ck + r - 512 > qlocal) st[r] = -1e30f;
            s[t] = st;
        }
        float mc = -1e30f;
#pragma unroll
        for (int t = 0; t < 8; t++)
#pragma unroll
            for (int r = 0; r < 4; r++) mc = fmaxf(mc, s[t][r]);
        mc = fmaxf(mc, __shfl_xor(mc, 16));
        mc = fmaxf(mc, __shfl_xor(mc, 32));
        float mn = fmaxf(m_, mc);
        float alpha = __expf(m_ - mn);
        m_ = mn;
        float su = 0.f;
#pragma unroll
        for (int t = 0; t < 8; t++) {
            union { u16 h[4]; uint2 v; } pk;
#pragma unroll
            for (int r = 0; r < 4; r++) {
                float p = __expf(s[t][r] - mn);
                su += p;
                pk.h[r] = f2bf(p);
            }
            *(uint2*)&pt[l15][t*16 + quad*4] = pk.v;
        }
        su += __shfl_xor(su, 16);
        su += __shfl_xor(su, 32);
        l_ = l_ * alpha + su;
#pragma unroll
        for (int t = 0; t < 4; t++)
#pragma unroll
            for (int r = 0; r < 4; r++) O[t][r] *= alpha;
#pragma unroll
        for (int g = 0; g < 4; g++) {
            short8 pf = *(const short8*)&pt[l15][g*32 + quad*8];
#pragma unroll
            for (int t = 0; t < 4; t++) {
                short8 vf = *(const short8*)&Vs[(t*16 + l15) * 128 + ((g*4 + quad) ^ swz) * 8];
                O[t] = __builtin_amdgcn_mfma_f32_16x16x32_bf16(vf, pf, O[t], 0, 0, 0);
            }
        }
    }
    float inv = 1.f / l_;
    u16* op = o + (size_t)(b*NSEQ + w0*WIN + qt*16 + l15) * DIM + hh*64;
#pragma unroll
    for (int t = 0; t < 4; t++) {
        union { u16 h[4]; uint2 v; } pk;
#pragma unroll
        for (int r = 0; r < 4; r++) pk.h[r] = f2bf(O[t][r] * inv);
        *(uint2*)(op + t*16 + quad*4) = pk.v;
    }
}

// ---------------- launch ----------------
extern "C" void kernel_launch(void* const* d_in, const int* in_sizes, int n_in,
                              void* d_out, int out_size, void* d_ws, size_t ws_size,
                              hipStream_t stream) {
    const float* x      = (const float*)d_in[0];
    const float* ln1_w  = (const float*)d_in[1];
    const float* ln1_b  = (const float*)d_in[2];
    const float* w_qkv  = (const float*)d_in[3];
    const float* w_out  = (const float*)d_in[4];
    const float* ln2_w  = (const float*)d_in[5];
    const float* w_ff1  = (const float*)d_in[6];
    const float* w_ff2  = (const float*)d_in[7];
    float* out = (float*)d_out;

    static bool cfg = false;
    if (!cfg) {
        hipFuncSetAttribute((const void*)gemm_k<2>,  hipFuncAttributeMaxDynamicSharedMemorySize, 73728);
        hipFuncSetAttribute((const void*)gemm_k<3>,  hipFuncAttributeMaxDynamicSharedMemorySize, 73728);
        hipFuncSetAttribute((const void*)gemm_mn128, hipFuncAttributeMaxDynamicSharedMemorySize, 73728);
        cfg = true;
    }

    char* ws = (char*)d_ws;
    size_t off = 0;
    auto alloc = [&](size_t bytes) { size_t o = off; off += (bytes + 255) & ~(size_t)255; return o; };
    size_t off_wqt  = alloc((size_t)QKV_N  * DIM * 2);
    size_t off_wot  = alloc((size_t)DIM    * DIM * 2);
    size_t off_wf1t = alloc((size_t)FF1_NP * DIM * 2);
    size_t off_wf2t = alloc((size_t)DIM    * INNER_P * 2);
    size_t off_h    = alloc((size_t)ROWS * DIM * 2);
    size_t sz_qkv = (size_t)ROWS * QKV_N * 2;
    size_t sz_vt  = (size_t)BATCH * HEADS * DH * NSEQ * 2;
    size_t off_qkv  = alloc(sz_qkv);
    size_t off_vt   = alloc(sz_vt);
    size_t off_o    = alloc((size_t)ROWS * DIM * 2);
    size_t off_x1   = alloc((size_t)ROWS * DIM * 4);
    size_t off_ag   = alloc((size_t)ROWS * INNER_P * 2);

    u16* wqt  = (u16*)(ws + off_wqt);
    u16* wot  = (u16*)(ws + off_wot);
    u16* wf1t = (u16*)(ws + off_wf1t);
    u16* wf2t = (u16*)(ws + off_wf2t);
    u16* h    = (u16*)(ws + off_h);
    u16* qkv  = (u16*)(ws + off_qkv);
    u16* vt   = (u16*)(ws + off_vt);
    u16* o    = (u16*)(ws + off_o);
    float* x1 = (float*)(ws + off_x1);
    u16* ag   = (u16*)(ws + off_ag);

    // 0) transpose+cast weights -> bf16 [N][K]; ff1 column-interleaved (a,g) pairs
    wtrans_kernel<false><<<dim3(32, 96),  256, 0, stream>>>(w_qkv, wqt,  DIM,   QKV_N, DIM,     QKV_N);
    wtrans_kernel<false><<<dim3(32, 32),  256, 0, stream>>>(w_out, wot,  DIM,   DIM,   DIM,     DIM);
    wtrans_kernel<true ><<<dim3(32, 176), 256, 0, stream>>>(w_ff1, wf1t, DIM,   FF1_N, DIM,     FF1_NP);
    wtrans_kernel<false><<<dim3(88, 32),  256, 0, stream>>>(w_ff2, wf2t, INNER, DIM,   INNER_P, DIM);

    // 1) LN1
    ln_kernel<<<ROWS, 256, 0, stream>>>(x, ln1_w, ln1_b, h);
    // 2) qkv = h @ w_qkv, rotary+scale fused (128x256 ring-3, 2 blocks/CU, 768 blocks)
    gemm_k<2><<<(ROWS/128) * (QKV_N/256), 256, 73728, stream>>>(h, wqt, qkv, QKV_N, DIM);
    // 3) V transpose
    vtrans_kernel<<<BATCH * HEADS * (NSEQ / 64), 256, 0, stream>>>(qkv, vt);
    // 4) attention
    attn_kernel<<<BATCH * HEADS * 8 * 8, 256, 0, stream>>>(qkv, vt, o);
    // 5) x1 = o @ w_out + x  (256x128 ring-3, 2 blocks/CU)
    gemm_mn128<<<256, 256, 73728, stream>>>(o, wot, x, x1, DIM, DIM);
    // 6) h2 = LN2(x1)
    ln_kernel<<<ROWS, 256, 0, stream>>>(x1, ln2_w, nullptr, h);
    // 7) ag = geglu(h2 @ w_ff1) fused, writes [8192 x 2816] (128x256 ring-3, 1408 blocks)
    gemm_k<3><<<(ROWS/128) * (FF1_NP/256), 256, 73728, stream>>>(h, wf1t, ag, FF1_NP, DIM);
    // 8) out = ag @ w_ff2 + x1  (256x128 ring-3, 2 blocks/CU)
    gemm_mn128<<<256, 256, 73728, stream>>>(ag, wf2t, x1, out, DIM, INNER_P);

    (void)in_sizes; (void)n_in; (void)out_size; (void)ws_size;
}